// Round 1
// baseline (326.100 us; speedup 1.0000x reference)
//
#include <hip/hip_runtime.h>

#define NN 2048      // nodes per batch
#define FF 128       // features per node
#define KK 16        // top-K
#define INF_KEY 0xFFFFFFFFFFFFFFFFull

// ---------- wave64 min-reduce via DPP (VALU pipe, no LDS/permute) ----------
__device__ __forceinline__ unsigned wave_min_u32(unsigned x) {
    int v = (int)x, t;
    t = __builtin_amdgcn_update_dpp(v, v, 0x111, 0xf, 0xf, false); // row_shr:1
    v = ((unsigned)t < (unsigned)v) ? t : v;
    t = __builtin_amdgcn_update_dpp(v, v, 0x112, 0xf, 0xf, false); // row_shr:2
    v = ((unsigned)t < (unsigned)v) ? t : v;
    t = __builtin_amdgcn_update_dpp(v, v, 0x114, 0xf, 0xf, false); // row_shr:4
    v = ((unsigned)t < (unsigned)v) ? t : v;
    t = __builtin_amdgcn_update_dpp(v, v, 0x118, 0xf, 0xf, false); // row_shr:8
    v = ((unsigned)t < (unsigned)v) ? t : v;
    t = __builtin_amdgcn_update_dpp(v, v, 0x142, 0xf, 0xf, false); // row_bcast:15
    v = ((unsigned)t < (unsigned)v) ? t : v;
    t = __builtin_amdgcn_update_dpp(v, v, 0x143, 0xf, 0xf, false); // row_bcast:31
    v = ((unsigned)t < (unsigned)v) ? t : v;
    return (unsigned)__builtin_amdgcn_readlane(v, 63);
}

// Kernel 1: dense zero of the whole adjacency at pure stream BW (~42 us for
// 268 MB at the 6.4-6.6 TB/s the harness's own fillBuffer demonstrates).
__global__ __launch_bounds__(256) void zero_adj(float4* __restrict__ out4, int n4)
{
    const float4 z = make_float4(0.f, 0.f, 0.f, 0.f);
    const int stride = gridDim.x * 256;
    for (int i = blockIdx.x * 256 + threadIdx.x; i < n4; i += stride)
        out4[i] = z;
}

// Kernel 2: sparse top-16 compute. Only rows < 1024 can be active (tau < 1024),
// so grid.y = 256 row-quads. Inactive blocks exit after one scalar load.
// Active rows run the verified one-pass per-lane sorted top-4 queue + 16 DPP
// extraction rounds, then scatter <=16 single-float 1.0 stores (causal j < i).
// d2 uses strict-IEEE non-contracted ops; key order == jax top_k (d2, index)
// lexicographic -> absmax 0 (logic byte-identical to the verified kernel).
__global__ __launch_bounds__(256) void knn_scatter(
    const float* __restrict__ nodes,
    const int*   __restrict__ T_arr,
    const int*   __restrict__ tau_arr,
    float*       __restrict__ adj)
{
    const int b    = blockIdx.x;
    const int i0   = blockIdx.y << 2;
    const int tid  = threadIdx.x;
    const int wave = tid >> 6;
    const int lane = tid & 63;

    const int tau = tau_arr[b];
    if (i0 >= tau) return;                    // fill kernel already zeroed

    const int T = T_arr[b];
    const int M = T + tau;                    // src_valid: j < M (<= 2046)

    __shared__ float sx[NN], sy[NN], sz[NN];  // 24 KiB, SoA: conflict-free
    for (int j = tid; j < M; j += 256) {
        const float* p = nodes + ((size_t)b * NN + j) * FF;
        sx[j] = p[0];
        sy[j] = p[1];
        sz[j] = p[2];
    }
    __syncthreads();

    const int i = i0 + wave;
    if (i >= tau) return;                     // inactive row: nothing to write

    float* row = adj + ((size_t)b * NN + i) * NN;
    const int g = T + i;                      // sink global index (< M always)
    const float sxv = sx[g], syv = sy[g], szv = sz[g];

    // ---- one-pass build of per-lane sorted top-4 queue ----
    unsigned long long q0 = INF_KEY, q1 = INF_KEY, q2 = INF_KEY, q3 = INF_KEY;
    const int S = (M + 63) >> 6;
    #pragma unroll 4
    for (int s = 0; s < S; ++s) {
        const int j = lane + (s << 6);
        if (j < M) {
            float dx = __fsub_rn(sxv, sx[j]);
            float dy = __fsub_rn(syv, sy[j]);
            float dz = __fsub_rn(szv, sz[j]);
            float d2 = __fadd_rn(__fadd_rn(__fmul_rn(dx, dx), __fmul_rn(dy, dy)),
                                 __fmul_rn(dz, dz));
            unsigned long long key =
                ((unsigned long long)__float_as_uint(d2) << 32) | (unsigned)(j + 1);
            if (key < q3) {
                q3 = key;
                unsigned long long t;
                if (q3 < q2) { t = q2; q2 = q3; q3 = t; }
                if (q2 < q1) { t = q1; q1 = q2; q2 = t; }
                if (q1 < q0) { t = q0; q0 = q1; q1 = t; }
            }
        }
    }

    // ---- 16 extraction rounds: DPP min on head d2 + ballot index resolve ----
    unsigned long long lastpop = 0;
    for (int k = 0; k < KK; ++k) {
        const unsigned hd = (unsigned)(q0 >> 32);
        const unsigned m  = wave_min_u32(hd);
        if (m == 0xFFFFFFFFu) break;          // all lanes exhausted

        const unsigned long long mask = __ballot(hd == m);
        unsigned jwin;
        if (__popcll(mask) == 1) {            // unique head d2 (common case)
            const int w = __builtin_ctzll(mask);
            jwin = (unsigned)__builtin_amdgcn_readlane((int)(unsigned)q0, w);
        } else {                              // cross-lane d2 tie (rare)
            unsigned jc = (hd == m) ? (unsigned)q0 : 0xFFFFFFFFu;
            jwin = wave_min_u32(jc);
        }
        const int j = (int)jwin - 1;

        if (lane == 0 && j < i)               // causal: scatter a single 1.0
            row[j] = 1.0f;

        if (hd == m && (unsigned)q0 == jwin) {  // pop on the winner lane
            lastpop = ((unsigned long long)m << 32) | jwin;
            q0 = q1; q1 = q2; q2 = q3; q3 = INF_KEY;
            if (q0 == INF_KEY) {              // rare: >4 global hits this lane
                unsigned long long best = INF_KEY;
                for (int s2 = 0; s2 < S; ++s2) {
                    const int jj = lane + (s2 << 6);
                    if (jj < M) {
                        float dx = __fsub_rn(sxv, sx[jj]);
                        float dy = __fsub_rn(syv, sy[jj]);
                        float dz = __fsub_rn(szv, sz[jj]);
                        float d2 = __fadd_rn(
                            __fadd_rn(__fmul_rn(dx, dx), __fmul_rn(dy, dy)),
                            __fmul_rn(dz, dz));
                        unsigned long long kk =
                            ((unsigned long long)__float_as_uint(d2) << 32)
                            | (unsigned)(jj + 1);
                        if (kk > lastpop && kk < best) best = kk;
                    }
                }
                q0 = best;
            }
        }
    }
}

extern "C" void kernel_launch(void* const* d_in, const int* in_sizes, int n_in,
                              void* d_out, int out_size, void* d_ws, size_t ws_size,
                              hipStream_t stream) {
    const float* nodes = (const float*)d_in[0];
    const int*   T     = (const int*)d_in[1];
    const int*   taus  = (const int*)d_in[2];
    float*       adj   = (float*)d_out;
    const int B = in_sizes[1];               // T has B elements (16)

    // 1) dense zero of the full adjacency (268 MB) at stream BW
    const int n4 = (int)(((size_t)B * NN * NN) / 4);
    zero_adj<<<dim3(2048), dim3(256), 0, stream>>>((float4*)adj, n4);

    // 2) sparse top-K scatter: only rows < 1024 can be active (tau < 1024)
    dim3 grid(B, 1024 / 4);                  // 16 x 256 blocks, 256 thr each
    knn_scatter<<<grid, dim3(256), 0, stream>>>(nodes, T, taus, adj);
}

// Round 3
// 281.295 us; speedup vs baseline: 1.1593x; 1.1593x over previous
//
#include <hip/hip_runtime.h>

#define NN 2048      // nodes per batch
#define FF 128       // features per node
#define KK 16        // top-K
#define INF_KEY 0xFFFFFFFFFFFFFFFFull

typedef float f32x4 __attribute__((ext_vector_type(4)));  // clang vector: ok for
                                                          // __builtin_nontemporal_store

// ---------- wave64 min-reduce via DPP (VALU pipe, no LDS/permute) ----------
__device__ __forceinline__ unsigned wave_min_u32(unsigned x) {
    int v = (int)x, t;
    t = __builtin_amdgcn_update_dpp(v, v, 0x111, 0xf, 0xf, false); // row_shr:1
    v = ((unsigned)t < (unsigned)v) ? t : v;
    t = __builtin_amdgcn_update_dpp(v, v, 0x112, 0xf, 0xf, false); // row_shr:2
    v = ((unsigned)t < (unsigned)v) ? t : v;
    t = __builtin_amdgcn_update_dpp(v, v, 0x114, 0xf, 0xf, false); // row_shr:4
    v = ((unsigned)t < (unsigned)v) ? t : v;
    t = __builtin_amdgcn_update_dpp(v, v, 0x118, 0xf, 0xf, false); // row_shr:8
    v = ((unsigned)t < (unsigned)v) ? t : v;
    t = __builtin_amdgcn_update_dpp(v, v, 0x142, 0xf, 0xf, false); // row_bcast:15
    v = ((unsigned)t < (unsigned)v) ? t : v;
    t = __builtin_amdgcn_update_dpp(v, v, 0x143, 0xf, 0xf, false); // row_bcast:31
    v = ((unsigned)t < (unsigned)v) ? t : v;
    return (unsigned)__builtin_amdgcn_readlane(v, 63);
}

// Fused: one block = 8 rows of one batch (512 thr, 8 waves). launch_bounds
// (512,8) forces VGPR<=64 -> 4 blocks/CU = 32 waves/CU (occupancy cap; was
// 24). Inactive blocks stream 64KB zeros (nontemporal: keep the 268MB write
// stream out of L2 so the 16MB nodes set stays cached for staging). Active
// rows: verified one-pass per-lane sorted top-4 queue + 16 DPP extraction
// rounds + 2KB LDS word table -> coalesced float4 row stores. d2 is strict-
// IEEE non-contracted; key order == jax top_k (d2,index) -> absmax 0.
__global__ __launch_bounds__(512, 8) void knn_adj_fused(
    const float* __restrict__ nodes,
    const int*   __restrict__ T_arr,
    const int*   __restrict__ tau_arr,
    float*       __restrict__ adj)
{
    const int b    = blockIdx.x;
    const int i0   = blockIdx.y << 3;
    const int tid  = threadIdx.x;
    const int wave = tid >> 6;
    const int lane = tid & 63;

    const int tau = tau_arr[b];
    float* block_out = adj + ((size_t)b * NN + i0) * NN;

    if (i0 >= tau) {                          // whole block inactive: 64 KB zeros
        const f32x4 z = (f32x4){0.f, 0.f, 0.f, 0.f};
        f32x4* out4 = (f32x4*)block_out;
        #pragma unroll
        for (int t = 0; t < 8; ++t)
            __builtin_nontemporal_store(z, &out4[tid + (t << 9)]);
        return;
    }

    const int T = T_arr[b];
    const int M = T + tau;                    // src_valid: j < M (<= 2046)

    __shared__ float sx[NN], sy[NN], sz[NN];  // 24 KiB, SoA: conflict-free
    __shared__ unsigned swords[8][64];        // 2 KiB: per-wave column words
    for (int j = tid; j < M; j += 512) {
        const float* p = nodes + ((size_t)b * NN + j) * FF;
        sx[j] = p[0];
        sy[j] = p[1];
        sz[j] = p[2];
    }
    __syncthreads();

    const int i = i0 + wave;
    f32x4* out4 = (f32x4*)(block_out + (size_t)wave * NN);

    if (i >= tau) {                           // inactive row in active block
        const f32x4 z = (f32x4){0.f, 0.f, 0.f, 0.f};
        #pragma unroll
        for (int t = 0; t < 8; ++t)
            __builtin_nontemporal_store(z, &out4[(t << 6) + lane]);
        return;
    }

    const int g = T + i;                      // sink global index (< M always)
    const float sxv = sx[g], syv = sy[g], szv = sz[g];

    // ---- one-pass build of per-lane sorted top-4 queue ----
    unsigned long long q0 = INF_KEY, q1 = INF_KEY, q2 = INF_KEY, q3 = INF_KEY;
    const int S     = (M + 63) >> 6;
    const int Sfull = M >> 6;                 // iterations with all lanes valid
    #pragma unroll 4
    for (int s = 0; s < Sfull; ++s) {
        const int j = lane + (s << 6);
        float dx = __fsub_rn(sxv, sx[j]);
        float dy = __fsub_rn(syv, sy[j]);
        float dz = __fsub_rn(szv, sz[j]);
        float d2 = __fadd_rn(__fadd_rn(__fmul_rn(dx, dx), __fmul_rn(dy, dy)),
                             __fmul_rn(dz, dz));
        unsigned long long key =
            ((unsigned long long)__float_as_uint(d2) << 32) | (unsigned)(j + 1);
        if (key < q3) {
            q3 = key;
            unsigned long long t;
            if (q3 < q2) { t = q2; q2 = q3; q3 = t; }
            if (q2 < q1) { t = q1; q1 = q2; q2 = t; }
            if (q1 < q0) { t = q0; q0 = q1; q1 = t; }
        }
    }
    {                                         // tail (same j order -> identical)
        const int j = lane + (Sfull << 6);
        if (j < M) {
            float dx = __fsub_rn(sxv, sx[j]);
            float dy = __fsub_rn(syv, sy[j]);
            float dz = __fsub_rn(szv, sz[j]);
            float d2 = __fadd_rn(__fadd_rn(__fmul_rn(dx, dx), __fmul_rn(dy, dy)),
                                 __fmul_rn(dz, dz));
            unsigned long long key =
                ((unsigned long long)__float_as_uint(d2) << 32) | (unsigned)(j + 1);
            if (key < q3) {
                q3 = key;
                unsigned long long t;
                if (q3 < q2) { t = q2; q2 = q3; q3 = t; }
                if (q2 < q1) { t = q1; q1 = q2; q2 = t; }
                if (q1 < q0) { t = q0; q0 = q1; q1 = t; }
            }
        }
    }

    // ---- 16 extraction rounds: DPP min on head d2 + ballot index resolve ----
    unsigned colmask = 0;                     // this lane's cols [32*lane, +32)
    unsigned long long lastpop = 0;
    for (int k = 0; k < KK; ++k) {
        const unsigned hd = (unsigned)(q0 >> 32);
        const unsigned m  = wave_min_u32(hd);
        if (m == 0xFFFFFFFFu) break;          // all lanes exhausted

        const unsigned long long mask = __ballot(hd == m);
        unsigned jwin;
        if (__popcll(mask) == 1) {            // unique head d2 (common case)
            const int w = __builtin_ctzll(mask);
            jwin = (unsigned)__builtin_amdgcn_readlane((int)(unsigned)q0, w);
        } else {                              // cross-lane d2 tie (rare)
            unsigned jc = (hd == m) ? (unsigned)q0 : 0xFFFFFFFFu;
            jwin = wave_min_u32(jc);
        }
        const int j = (int)jwin - 1;

        if (j < i && (j >> 5) == lane)        // causal + word ownership
            colmask |= 1u << (j & 31);

        if (hd == m && (unsigned)q0 == jwin) {  // pop on the winner lane
            lastpop = ((unsigned long long)m << 32) | jwin;
            q0 = q1; q1 = q2; q2 = q3; q3 = INF_KEY;
            if (q0 == INF_KEY) {              // rare: >4 global hits this lane
                unsigned long long best = INF_KEY;
                for (int s2 = 0; s2 < S; ++s2) {
                    const int jj = lane + (s2 << 6);
                    if (jj < M) {
                        float dx = __fsub_rn(sxv, sx[jj]);
                        float dy = __fsub_rn(syv, sy[jj]);
                        float dz = __fsub_rn(szv, sz[jj]);
                        float d2 = __fadd_rn(
                            __fadd_rn(__fmul_rn(dx, dx), __fmul_rn(dy, dy)),
                            __fmul_rn(dz, dz));
                        unsigned long long kk =
                            ((unsigned long long)__float_as_uint(d2) << 32)
                            | (unsigned)(jj + 1);
                        if (kk > lastpop && kk < best) best = kk;
                    }
                }
                q0 = best;
            }
        }
    }

    // ---- route words through LDS (same wave: no barrier), stream the row ----
    swords[wave][lane] = colmask;
    #pragma unroll
    for (int k = 0; k < 8; ++k) {
        // cols c = 256k + 4*lane .. +3 ; word = 8k + (lane>>3) (broadcast read)
        const unsigned w   = swords[wave][(k << 3) + (lane >> 3)];
        const unsigned nib = (w >> ((lane & 7) << 2)) & 0xFu;
        f32x4 v;
        v.x = (nib & 1u) ? 1.0f : 0.0f;
        v.y = (nib & 2u) ? 1.0f : 0.0f;
        v.z = (nib & 4u) ? 1.0f : 0.0f;
        v.w = (nib & 8u) ? 1.0f : 0.0f;
        __builtin_nontemporal_store(v, &out4[(k << 6) + lane]);
    }
}

extern "C" void kernel_launch(void* const* d_in, const int* in_sizes, int n_in,
                              void* d_out, int out_size, void* d_ws, size_t ws_size,
                              hipStream_t stream) {
    const float* nodes = (const float*)d_in[0];
    const int*   T     = (const int*)d_in[1];
    const int*   taus  = (const int*)d_in[2];
    float*       adj   = (float*)d_out;
    const int B = in_sizes[1];               // T has B elements (16)

    dim3 grid(B, NN / 8);                    // 16 x 256 blocks, 512 thr each
    knn_adj_fused<<<grid, dim3(512), 0, stream>>>(nodes, T, taus, adj);
}